// Round 19
// baseline (106.847 us; speedup 1.0000x reference)
//
#include <hip/hip_runtime.h>

// Problem constants (fixed by setup_inputs).
constexpr int L  = 512;   // sequence length
constexpr int CS = 384;   // c_s
constexpr int CH = 32;    // c_h
constexpr int CZ = 128;   // c_z
constexpr float LN_EPS = 1e-5f;

typedef float f2 __attribute__((ext_vector_type(2)));
typedef float f4 __attribute__((ext_vector_type(4)));

// ---------------------------------------------------------------------------
// Kernel 1 (v2): LayerNorm + dual projection + mask.  (R11-exact)
// ---------------------------------------------------------------------------
__global__ __launch_bounds__(64) void k_ln_proj(
    const float* __restrict__ s, const int* __restrict__ mask,
    const float* __restrict__ ln_scale, const float* __restrict__ ln_bias,
    const float* __restrict__ w1, const float* __restrict__ b1,
    const float* __restrict__ w2, const float* __restrict__ b2,
    float* __restrict__ a, float* __restrict__ b)
{
    __shared__ float sn_lds[CS];
    const int lane = threadIdx.x;
    const int row  = blockIdx.x;

    const float* srow = s + row * CS;
    float v[6];
    float sum = 0.f, sumsq = 0.f;
#pragma unroll
    for (int q = 0; q < 6; ++q) {
        v[q] = srow[lane + 64 * q];
        sum   += v[q];
        sumsq += v[q] * v[q];
    }
#pragma unroll
    for (int off = 32; off; off >>= 1) {
        sum   += __shfl_xor(sum, off);
        sumsq += __shfl_xor(sumsq, off);
    }
    const float mu   = sum * (1.f / CS);
    const float var  = sumsq * (1.f / CS) - mu * mu;
    const float rstd = rsqrtf(var + LN_EPS);
#pragma unroll
    for (int q = 0; q < 6; ++q) {
        const int k = lane + 64 * q;
        sn_lds[k] = (v[q] - mu) * rstd * ln_scale[k] + ln_bias[k];
    }
    __syncthreads();

    const int c    = lane & 31;
    const int half = lane >> 5;
    const float* W  = half ? w2 : w1;
    const float* Bv = half ? b2 : b1;
    float acc = 0.f;
#pragma unroll 4
    for (int k = 0; k < CS; ++k)
        acc += sn_lds[k] * W[k * CH + c];
    const float m = (float)mask[row];
    const float outv = (acc + Bv[c]) * m;
    (half ? b : a)[row * CH + c] = outv;
}

// ---------------------------------------------------------------------------
// Kernel 2: G[i][e][z] = sum_c a[i][c] * w_out[(c*CH+e)*CZ + z].  (R15-exact)
// ---------------------------------------------------------------------------
__global__ __launch_bounds__(512) void k_G(
    const float* __restrict__ a, const float* __restrict__ w_out,
    float* __restrict__ G)
{
    const int i0 = blockIdx.x * 2;
    const int t  = threadIdx.x;
    const int e  = t >> 4;             // 0..31
    const int zo = t & 15;             // z-octet: z = 8*zo .. 8*zo+7

    float a0[CH], a1[CH];
#pragma unroll
    for (int c = 0; c < CH; ++c) {
        a0[c] = a[i0 * CH + c];        // wave-uniform -> broadcast
        a1[c] = a[(i0 + 1) * CH + c];
    }

    const float* wbase = w_out + (size_t)e * CZ + 8 * zo;   // + c*CH*CZ per c
    f4 g00 = 0.f, g01 = 0.f, g10 = 0.f, g11 = 0.f;
#pragma unroll
    for (int c = 0; c < CH; ++c) {
        const f4 w0 = *(const f4*)(wbase + (size_t)c * (CH * CZ));
        const f4 w1 = *(const f4*)(wbase + (size_t)c * (CH * CZ) + 4);
        g00 += a0[c] * w0;  g01 += a0[c] * w1;
        g10 += a1[c] * w0;  g11 += a1[c] * w1;
    }

    float* Gp0 = G + (size_t)i0 * (CH * CZ) + e * CZ + 8 * zo;
    *(f4*)(Gp0)     = g00;
    *(f4*)(Gp0 + 4) = g01;
    float* Gp1 = Gp0 + CH * CZ;
    *(f4*)(Gp1)     = g10;
    *(f4*)(Gp1 + 4) = g11;
}

// ---------------------------------------------------------------------------
// Kernel 3: z[i,j,:] = sum_e b[j,e] * G[i,e,:] + b_out  ->  ws2 (d_ws).
// R17-A-exact (measured 26.7 us into d_ws). Writes the FINAL out-layout
// (ws2[i][j][z]), so pass B is a pure linear memcpy — no permutation.
// ---------------------------------------------------------------------------
__global__ __launch_bounds__(512, 2) void k_mainWS(
    const float* __restrict__ b, const float* __restrict__ G,
    const float* __restrict__ b_out, float* __restrict__ dest)
{
    __shared__ float b_lds[L][CH];     // 64 KB: entire b matrix

    const int i    = blockIdx.x;
    const int t    = threadIdx.x;
    const int wave = t >> 6;
    const int lane = t & 63;
    const int half = lane >> 5;        // which j of the wave's pair
    const int zq   = lane & 31;        // z-quad: z = 4*zq

    // Stage all of b: 16384 floats = 512 threads x 8 float4.
#pragma unroll
    for (int k = 0; k < 8; ++k)
        ((f4*)b_lds)[t + k * 512] = ((const f4*)b)[t + k * 512];

    // G[i] z-quad column for this lane: 128 VGPRs (f4-coalesced, L2/L3-hot).
    f4 G_reg[CH];
    const float* Gi = G + (size_t)i * (CH * CZ) + 4 * zq;
#pragma unroll
    for (int e = 0; e < CH; ++e)
        G_reg[e] = *(const f4*)(Gi + e * CZ);

    const f4 bo = ((const f4*)b_out)[zq];
    float* op = dest + (size_t)i * (L * CZ);

    __syncthreads();

#pragma unroll 2
    for (int s = 0; s < 32; ++s) {
        const int j = s * 16 + 2 * wave + half;
        const f4* bp = (const f4*)&b_lds[j][0];   // 2-way row split (free)
        f4 acc = bo;
#pragma unroll
        for (int q = 0; q < 8; ++q) {
            const f4 r = bp[q];
            acc += r.x * G_reg[4 * q + 0];
            acc += r.y * G_reg[4 * q + 1];
            acc += r.z * G_reg[4 * q + 2];
            acc += r.w * G_reg[4 * q + 3];
        }
        *(f4*)(op + (size_t)j * CZ + 4 * zq) = acc;
    }
}

// ---------------------------------------------------------------------------
// Kernel 4: pure linear copy ws2 -> out, prefill-recipe (R13: 7.1 TB/s into
// d_out with this exact shape): grid 1024 x 256 thr (4 blocks/CU, 32
// waves/CU, tiny VGPR), each block sweeps one 128 KB contiguous region.
// Source is L3-resident (134 MB just written < 256 MB IC) and read linearly.
// ---------------------------------------------------------------------------
__global__ __launch_bounds__(256) void k_copy(
    const float* __restrict__ src, float* __restrict__ dst)
{
    const size_t base = (size_t)blockIdx.x * 8192 + threadIdx.x;  // f4 units
    const f4* s = (const f4*)src + base;
    f4*       d = (f4*)dst + base;
#pragma unroll 8
    for (int k = 0; k < 32; ++k)
        d[k * 256] = s[k * 256];
}

// ---------------------------------------------------------------------------
extern "C" void kernel_launch(void* const* d_in, const int* in_sizes, int n_in,
                              void* d_out, int out_size, void* d_ws, size_t ws_size,
                              hipStream_t stream) {
    const float* s        = (const float*)d_in[0];
    const int*   mask     = (const int*)d_in[1];
    const float* ln_scale = (const float*)d_in[2];
    const float* ln_bias  = (const float*)d_in[3];
    const float* w1       = (const float*)d_in[4];
    const float* b1       = (const float*)d_in[5];
    const float* w2       = (const float*)d_in[6];
    const float* b2       = (const float*)d_in[7];
    const float* w_out    = (const float*)d_in[8];
    const float* b_out    = (const float*)d_in[9];
    float* out = (float*)d_out;

    // Workspace: a [16K], b [16K], G [2M floats], ws2 [33.5M floats, final
    // out-layout].
    float* a   = (float*)d_ws;
    float* b   = a + L * CH;
    float* G   = b + L * CH;
    float* ws2 = G + (size_t)L * CH * CZ;

    k_ln_proj<<<L, 64, 0, stream>>>(s, mask, ln_scale, ln_bias,
                                    w1, b1, w2, b2, a, b);
    k_G<<<L / 2, 512, 0, stream>>>(a, w_out, G);
    k_mainWS<<<L, 512, 0, stream>>>(b, G, b_out, ws2);
    k_copy<<<1024, 256, 0, stream>>>(ws2, out);
}

// Round 20
// 92.746 us; speedup vs baseline: 1.1520x; 1.1520x over previous
//
#include <hip/hip_runtime.h>

// Problem constants (fixed by setup_inputs).
constexpr int L  = 512;   // sequence length
constexpr int CS = 384;   // c_s
constexpr int CH = 32;    // c_h
constexpr int CZ = 128;   // c_z
constexpr float LN_EPS = 1e-5f;

typedef float f2 __attribute__((ext_vector_type(2)));
typedef float f4 __attribute__((ext_vector_type(4)));

// ---------------------------------------------------------------------------
// Kernel 0 (DIAGNOSTIC): fill d_out with ADDRESS-DERIVED GARBAGE using R13's
// exact prefill structure (1024 blk x 256 thr, 8-12 VGPR, no LDS, 32
// back-to-back f4 stores/thread, block-linear 128 KB sweep). R13 (zeros) ran
// at 7.1 TB/s; fillBuffer (0xAA) at 6.6. If those were fast only because
// CONSTANT data compresses below the TCC boundary, this kernel — identical
// except non-uniform values — will run at the ~1.9 TB/s real-data wall
// (~70 us), proving R16's k_main is already at the d_out roofline.
// If it runs ~19 us, store-only kernels are fast for ANY data and the hunt
// moves to compute-kernel structure. Output overwritten by k_main below.
// ---------------------------------------------------------------------------
__global__ __launch_bounds__(256) void k_garbage(float* __restrict__ out)
{
    const size_t base = (size_t)blockIdx.x * 8192 + threadIdx.x;  // f4 units
    f4* d = (f4*)out + base;
#pragma unroll 8
    for (int k = 0; k < 32; ++k) {
        const unsigned idx = (unsigned)(base + (size_t)k * 256);
        const float x = (float)idx;                 // v_cvt_f32_u32
        f4 v;
        v.x = x;
        v.y = x * 1.0001f + 1.0f;
        v.z = x * 0.9999f + 2.0f;
        v.w = x + 3.0f;
        d[k * 256] = v;
    }
}

// ---------------------------------------------------------------------------
// Kernel 1 (v2): LayerNorm + dual projection + mask.  (R11-exact)
// ---------------------------------------------------------------------------
__global__ __launch_bounds__(64) void k_ln_proj(
    const float* __restrict__ s, const int* __restrict__ mask,
    const float* __restrict__ ln_scale, const float* __restrict__ ln_bias,
    const float* __restrict__ w1, const float* __restrict__ b1,
    const float* __restrict__ w2, const float* __restrict__ b2,
    float* __restrict__ a, float* __restrict__ b)
{
    __shared__ float sn_lds[CS];
    const int lane = threadIdx.x;
    const int row  = blockIdx.x;

    const float* srow = s + row * CS;
    float v[6];
    float sum = 0.f, sumsq = 0.f;
#pragma unroll
    for (int q = 0; q < 6; ++q) {
        v[q] = srow[lane + 64 * q];
        sum   += v[q];
        sumsq += v[q] * v[q];
    }
#pragma unroll
    for (int off = 32; off; off >>= 1) {
        sum   += __shfl_xor(sum, off);
        sumsq += __shfl_xor(sumsq, off);
    }
    const float mu   = sum * (1.f / CS);
    const float var  = sumsq * (1.f / CS) - mu * mu;
    const float rstd = rsqrtf(var + LN_EPS);
#pragma unroll
    for (int q = 0; q < 6; ++q) {
        const int k = lane + 64 * q;
        sn_lds[k] = (v[q] - mu) * rstd * ln_scale[k] + ln_bias[k];
    }
    __syncthreads();

    const int c    = lane & 31;
    const int half = lane >> 5;
    const float* W  = half ? w2 : w1;
    const float* Bv = half ? b2 : b1;
    float acc = 0.f;
#pragma unroll 4
    for (int k = 0; k < CS; ++k)
        acc += sn_lds[k] * W[k * CH + c];
    const float m = (float)mask[row];
    const float outv = (acc + Bv[c]) * m;
    (half ? b : a)[row * CH + c] = outv;
}

// ---------------------------------------------------------------------------
// Kernel 2: G[i][e][z] = sum_c a[i][c] * w_out[(c*CH+e)*CZ + z].  (R15-exact)
// ---------------------------------------------------------------------------
__global__ __launch_bounds__(512) void k_G(
    const float* __restrict__ a, const float* __restrict__ w_out,
    float* __restrict__ G)
{
    const int i0 = blockIdx.x * 2;
    const int t  = threadIdx.x;
    const int e  = t >> 4;             // 0..31
    const int zo = t & 15;             // z-octet: z = 8*zo .. 8*zo+7

    float a0[CH], a1[CH];
#pragma unroll
    for (int c = 0; c < CH; ++c) {
        a0[c] = a[i0 * CH + c];        // wave-uniform -> broadcast
        a1[c] = a[(i0 + 1) * CH + c];
    }

    const float* wbase = w_out + (size_t)e * CZ + 8 * zo;   // + c*CH*CZ per c
    f4 g00 = 0.f, g01 = 0.f, g10 = 0.f, g11 = 0.f;
#pragma unroll
    for (int c = 0; c < CH; ++c) {
        const f4 w0 = *(const f4*)(wbase + (size_t)c * (CH * CZ));
        const f4 w1 = *(const f4*)(wbase + (size_t)c * (CH * CZ) + 4);
        g00 += a0[c] * w0;  g01 += a0[c] * w1;
        g10 += a1[c] * w0;  g11 += a1[c] * w1;
    }

    float* Gp0 = G + (size_t)i0 * (CH * CZ) + e * CZ + 8 * zo;
    *(f4*)(Gp0)     = g00;
    *(f4*)(Gp0 + 4) = g01;
    float* Gp1 = Gp0 + CH * CZ;
    *(f4*)(Gp1)     = g10;
    *(f4*)(Gp1 + 4) = g11;
}

// ---------------------------------------------------------------------------
// Kernel 3: z[i,j,:] = sum_e b[j,e] * G[i,e,:] + b_out.  (R16-exact, best
// measured single-pass: 72.4 us total.)
// ---------------------------------------------------------------------------
__global__ __launch_bounds__(512, 2) void k_main(
    const float* __restrict__ b, const float* __restrict__ G,
    const float* __restrict__ b_out, float* __restrict__ out)
{
    __shared__ float b_lds[L][CH];     // 64 KB: entire b matrix

    const int i    = blockIdx.x;
    const int t    = threadIdx.x;
    const int wave = t >> 6;
    const int lane = t & 63;
    const int half = lane >> 5;        // which j of the wave's pair
    const int zq   = lane & 31;        // z-quad: z = 4*zq

    // Stage all of b: 16384 floats = 512 threads x 8 float4.
#pragma unroll
    for (int k = 0; k < 8; ++k)
        ((f4*)b_lds)[t + k * 512] = ((const f4*)b)[t + k * 512];

    // G[i] z-quad column for this lane: 128 VGPRs (f4-coalesced, L2/L3-hot).
    f4 G_reg[CH];
    const float* Gi = G + (size_t)i * (CH * CZ) + 4 * zq;
#pragma unroll
    for (int e = 0; e < CH; ++e)
        G_reg[e] = *(const f4*)(Gi + e * CZ);

    const f4 bo = ((const f4*)b_out)[zq];
    float* op = out + (size_t)i * (L * CZ);

    __syncthreads();

#pragma unroll 2
    for (int s = 0; s < 32; ++s) {
        const int j = s * 16 + 2 * wave + half;
        const f4* bp = (const f4*)&b_lds[j][0];   // 2-way row split (free)
        f4 acc = bo;
#pragma unroll
        for (int q = 0; q < 8; ++q) {
            const f4 r = bp[q];
            acc += r.x * G_reg[4 * q + 0];
            acc += r.y * G_reg[4 * q + 1];
            acc += r.z * G_reg[4 * q + 2];
            acc += r.w * G_reg[4 * q + 3];
        }
        *(f4*)(op + (size_t)j * CZ + 4 * zq) = acc;
    }
}

// ---------------------------------------------------------------------------
extern "C" void kernel_launch(void* const* d_in, const int* in_sizes, int n_in,
                              void* d_out, int out_size, void* d_ws, size_t ws_size,
                              hipStream_t stream) {
    const float* s        = (const float*)d_in[0];
    const int*   mask     = (const int*)d_in[1];
    const float* ln_scale = (const float*)d_in[2];
    const float* ln_bias  = (const float*)d_in[3];
    const float* w1       = (const float*)d_in[4];
    const float* b1       = (const float*)d_in[5];
    const float* w2       = (const float*)d_in[6];
    const float* b2       = (const float*)d_in[7];
    const float* w_out    = (const float*)d_in[8];
    const float* b_out    = (const float*)d_in[9];
    float* out = (float*)d_out;

    // Workspace: a [512*32], b [512*32], G [512*32*128]  (8.125 MB total).
    float* a = (float*)d_ws;
    float* b = a + L * CH;
    float* G = b + L * CH;

    // Diagnostic: garbage-prefill of d_out (overwritten by k_main).
    k_garbage<<<1024, 256, 0, stream>>>(out);
    k_ln_proj<<<L, 64, 0, stream>>>(s, mask, ln_scale, ln_bias,
                                    w1, b1, w2, b2, a, b);
    k_G<<<L / 2, 512, 0, stream>>>(a, w_out, G);
    k_main<<<L, 512, 0, stream>>>(b, G, b_out, out);
}

// Round 21
// 71.779 us; speedup vs baseline: 1.4885x; 1.2921x over previous
//
#include <hip/hip_runtime.h>

// Problem constants (fixed by setup_inputs).
constexpr int L  = 512;   // sequence length
constexpr int CS = 384;   // c_s
constexpr int CH = 32;    // c_h
constexpr int CZ = 128;   // c_z
constexpr float LN_EPS = 1e-5f;

typedef float f2 __attribute__((ext_vector_type(2)));
typedef float f4 __attribute__((ext_vector_type(4)));

// ---------------------------------------------------------------------------
// Kernel 1 (v2): LayerNorm + dual projection + mask.  (R11-exact)
// ---------------------------------------------------------------------------
__global__ __launch_bounds__(64) void k_ln_proj(
    const float* __restrict__ s, const int* __restrict__ mask,
    const float* __restrict__ ln_scale, const float* __restrict__ ln_bias,
    const float* __restrict__ w1, const float* __restrict__ b1,
    const float* __restrict__ w2, const float* __restrict__ b2,
    float* __restrict__ a, float* __restrict__ b)
{
    __shared__ float sn_lds[CS];
    const int lane = threadIdx.x;
    const int row  = blockIdx.x;

    const float* srow = s + row * CS;
    float v[6];
    float sum = 0.f, sumsq = 0.f;
#pragma unroll
    for (int q = 0; q < 6; ++q) {
        v[q] = srow[lane + 64 * q];
        sum   += v[q];
        sumsq += v[q] * v[q];
    }
#pragma unroll
    for (int off = 32; off; off >>= 1) {
        sum   += __shfl_xor(sum, off);
        sumsq += __shfl_xor(sumsq, off);
    }
    const float mu   = sum * (1.f / CS);
    const float var  = sumsq * (1.f / CS) - mu * mu;
    const float rstd = rsqrtf(var + LN_EPS);
#pragma unroll
    for (int q = 0; q < 6; ++q) {
        const int k = lane + 64 * q;
        sn_lds[k] = (v[q] - mu) * rstd * ln_scale[k] + ln_bias[k];
    }
    __syncthreads();

    const int c    = lane & 31;
    const int half = lane >> 5;
    const float* W  = half ? w2 : w1;
    const float* Bv = half ? b2 : b1;
    float acc = 0.f;
#pragma unroll 4
    for (int k = 0; k < CS; ++k)
        acc += sn_lds[k] * W[k * CH + c];
    const float m = (float)mask[row];
    const float outv = (acc + Bv[c]) * m;
    (half ? b : a)[row * CH + c] = outv;
}

// ---------------------------------------------------------------------------
// Kernel 2: G[i][e][z] = sum_c a[i][c] * w_out[(c*CH+e)*CZ + z].  (R15-exact)
// ---------------------------------------------------------------------------
__global__ __launch_bounds__(512) void k_G(
    const float* __restrict__ a, const float* __restrict__ w_out,
    float* __restrict__ G)
{
    const int i0 = blockIdx.x * 2;
    const int t  = threadIdx.x;
    const int e  = t >> 4;             // 0..31
    const int zo = t & 15;             // z-octet: z = 8*zo .. 8*zo+7

    float a0[CH], a1[CH];
#pragma unroll
    for (int c = 0; c < CH; ++c) {
        a0[c] = a[i0 * CH + c];        // wave-uniform -> broadcast
        a1[c] = a[(i0 + 1) * CH + c];
    }

    const float* wbase = w_out + (size_t)e * CZ + 8 * zo;   // + c*CH*CZ per c
    f4 g00 = 0.f, g01 = 0.f, g10 = 0.f, g11 = 0.f;
#pragma unroll
    for (int c = 0; c < CH; ++c) {
        const f4 w0 = *(const f4*)(wbase + (size_t)c * (CH * CZ));
        const f4 w1 = *(const f4*)(wbase + (size_t)c * (CH * CZ) + 4);
        g00 += a0[c] * w0;  g01 += a0[c] * w1;
        g10 += a1[c] * w0;  g11 += a1[c] * w1;
    }

    float* Gp0 = G + (size_t)i0 * (CH * CZ) + e * CZ + 8 * zo;
    *(f4*)(Gp0)     = g00;
    *(f4*)(Gp0 + 4) = g01;
    float* Gp1 = Gp0 + CH * CZ;
    *(f4*)(Gp1)     = g10;
    *(f4*)(Gp1 + 4) = g11;
}

// ---------------------------------------------------------------------------
// Kernel 3 (v7): z[i,j,:] = sum_e b[j,e] * G[i,e,:] + b_out.
// 256-THREAD BLOCK SHAPE (single variable vs R16): every kernel ever
// measured fast into d_out (fillBuffer, R13 zero-prefill, R20 garbage) is a
// 256-thr block sweeping a 128 KB contiguous region; every ~2 TB/s compute
// writer was 512-thr. R17 proved the instruction mix is innocent (identical
// ISA: ws=27us, out=62us) — block shape is the last untested structural
// difference. grid = 1024: block = (i, j-half); 4 waves sweep 128 KB
// linearly at 4 KB/step (prefill's exact region/step size). Wave handles a
// j-pair per step (half=lane>>5, zq=lane&31 — R16-identical lane map);
// b_lds stages this block's 256 j-rows (32 KB); G[i] z-quad column in 128
// VGPRs; plain f4 stores.
// ---------------------------------------------------------------------------
__global__ __launch_bounds__(256) void k_main(
    const float* __restrict__ b, const float* __restrict__ G,
    const float* __restrict__ b_out, float* __restrict__ out)
{
    __shared__ float b_lds[256][CH];   // 32 KB: this block's j-half of b

    const int bid  = blockIdx.x;
    const int i    = bid >> 1;
    const int jh   = bid & 1;          // j-half: [jh*256, jh*256+256)
    const int t    = threadIdx.x;
    const int wave = t >> 6;           // 0..3
    const int lane = t & 63;
    const int half = lane >> 5;        // which j of the wave's pair
    const int zq   = lane & 31;        // z-quad: z = 4*zq

    // Stage this half of b: 8192 floats = 256 threads x 8 float4.
    const f4* bsrc = (const f4*)(b + (size_t)jh * 256 * CH);
#pragma unroll
    for (int k = 0; k < 8; ++k)
        ((f4*)b_lds)[t + k * 256] = bsrc[t + k * 256];

    // G[i] z-quad column for this lane: 128 VGPRs (f4-coalesced, L2/L3-hot).
    f4 G_reg[CH];
    const float* Gi = G + (size_t)i * (CH * CZ) + 4 * zq;
#pragma unroll
    for (int e = 0; e < CH; ++e)
        G_reg[e] = *(const f4*)(Gi + e * CZ);

    const f4 bo = ((const f4*)b_out)[zq];
    // Block's 128 KB output region: rows [jh*256, jh*256+256) of out[i].
    float* op = out + (size_t)i * (L * CZ) + (size_t)jh * 256 * CZ;

    __syncthreads();

#pragma unroll 2
    for (int s = 0; s < 32; ++s) {
        const int jl = s * 8 + 2 * wave + half;   // local j within the half
        const f4* bp = (const f4*)&b_lds[jl][0];  // 2-way row split (free)
        f4 acc = bo;
#pragma unroll
        for (int q = 0; q < 8; ++q) {
            const f4 r = bp[q];
            acc += r.x * G_reg[4 * q + 0];
            acc += r.y * G_reg[4 * q + 1];
            acc += r.z * G_reg[4 * q + 2];
            acc += r.w * G_reg[4 * q + 3];
        }
        // 4 KB contiguous per block-step (8 adjacent j-rows), linear sweep.
        *(f4*)(op + (size_t)jl * CZ + 4 * zq) = acc;
    }
}

// ---------------------------------------------------------------------------
extern "C" void kernel_launch(void* const* d_in, const int* in_sizes, int n_in,
                              void* d_out, int out_size, void* d_ws, size_t ws_size,
                              hipStream_t stream) {
    const float* s        = (const float*)d_in[0];
    const int*   mask     = (const int*)d_in[1];
    const float* ln_scale = (const float*)d_in[2];
    const float* ln_bias  = (const float*)d_in[3];
    const float* w1       = (const float*)d_in[4];
    const float* b1       = (const float*)d_in[5];
    const float* w2       = (const float*)d_in[6];
    const float* b2       = (const float*)d_in[7];
    const float* w_out    = (const float*)d_in[8];
    const float* b_out    = (const float*)d_in[9];
    float* out = (float*)d_out;

    // Workspace: a [512*32], b [512*32], G [512*32*128]  (8.125 MB total).
    float* a = (float*)d_ws;
    float* b = a + L * CH;
    float* G = b + L * CH;

    k_ln_proj<<<L, 64, 0, stream>>>(s, mask, ln_scale, ln_bias,
                                    w1, b1, w2, b2, a, b);
    k_G<<<L / 2, 512, 0, stream>>>(a, w_out, G);
    k_main<<<2 * L, 256, 0, stream>>>(b, G, b_out, out);
}